// Round 16
// baseline (432.994 us; speedup 1.0000x reference)
//
#include <hip/hip_runtime.h>
#include <hip/hip_bf16.h>

#define TSEQ 2048
#define BATCH 4
#define NH 16
#define NKV 4
#define HD 128
#define NQKV 3072
#define SCALE_ 0.08838834764831845f
#define LOG2E_ 1.44269504088896f

#if __has_builtin(__builtin_amdgcn_exp2f)
#define EXP2(x) __builtin_amdgcn_exp2f(x)
#else
#define EXP2(x) __expf((x) * 0.6931471805599453f)
#endif

typedef __bf16 bf16x8 __attribute__((ext_vector_type(8)));
typedef float f32x4 __attribute__((ext_vector_type(4)));

__device__ __forceinline__ unsigned short f2bf(float f) {
    union { float f; unsigned u; } v; v.f = f;
    unsigned r = v.u + 0x7fffu + ((v.u >> 16) & 1u);
    return (unsigned short)(r >> 16);
}
__device__ __forceinline__ float bf2f(unsigned short b) {
    union { unsigned u; float f; } v; v.u = ((unsigned)b) << 16; return v.f;
}

// ---------------- X fp32 -> bf16 (vectorized) ----------------
__global__ __launch_bounds__(256) void xconv(const float* __restrict__ in,
                                             unsigned short* __restrict__ out) {
    const size_t i = (size_t)blockIdx.x * 256 + threadIdx.x; // 4 floats per thread
    const float4 v = ((const float4*)in)[i];
    union { unsigned short u[4]; int2 p; } o;
    o.u[0] = f2bf(v.x); o.u[1] = f2bf(v.y); o.u[2] = f2bf(v.z); o.u[3] = f2bf(v.w);
    ((int2*)out)[i] = o.p;
}

// ------------- weight transpose f32 [K][inN] -> bf16 [inN-rows][K] -------------
// grid (inN/64, K/64), block 256
__global__ __launch_bounds__(256) void wtrans_kernel(const float* __restrict__ in,
                                                     unsigned short* __restrict__ out,
                                                     int inN, int K) {
    __shared__ unsigned short l[64][65];
    const int n0 = blockIdx.x * 64, k0 = blockIdx.y * 64;
    const int tid = threadIdx.x;
    const int r = tid >> 2, c0 = (tid & 3) * 16;
#pragma unroll
    for (int i = 0; i < 16; i += 4) {
        float4 v = *(const float4*)&in[(size_t)(k0 + r) * inN + n0 + c0 + i];
        l[c0 + i + 0][r] = f2bf(v.x);
        l[c0 + i + 1][r] = f2bf(v.y);
        l[c0 + i + 2][r] = f2bf(v.z);
        l[c0 + i + 3][r] = f2bf(v.w);
    }
    __syncthreads();
    unsigned short tmp[16];
#pragma unroll
    for (int i = 0; i < 16; ++i) tmp[i] = l[r][c0 + i];
    *(int4*)&out[(size_t)(n0 + r) * K + k0 + c0] = *(int4*)&tmp[0];
    *(int4*)&out[(size_t)(n0 + r) * K + k0 + c0 + 8] = *(int4*)&tmp[8];
}

// ---------------- bias concat ----------------
__global__ __launch_bounds__(256) void bias_concat(const float* __restrict__ bq,
                                                   const float* __restrict__ bk,
                                                   const float* __restrict__ bv,
                                                   float* __restrict__ out) {
    int i = blockIdx.x * 256 + threadIdx.x; // 3072
    out[i] = (i < 2048) ? bq[i] : ((i < 2560) ? bk[i - 2048] : bv[i - 2560]);
}

// ---------------- BMx256 counted-vmcnt GEMM (r7 skeleton, tile-parametrized) ----
// BM=256: r7-identical (O-proj, 256 blocks = 1 exact dispatch wave).
// BM=128: QKV GEMM -> 768 blocks = 3 exact waves (fixes 384-block 75% tail).
// BK=64, 8 waves (2M x 4N), wave tile (BM/2)x64.
template <int BM, bool BIAS, bool OUTBF16>
__global__ __launch_bounds__(512) void gemm256(const unsigned short* __restrict__ A,
                                               const unsigned short* __restrict__ Bt,
                                               const float* __restrict__ bias,
                                               void* __restrict__ Cout,
                                               int M, int N, int K, int mtiles) {
    constexpr int MREP = BM / 32;  // acc rows: 4 or 8
    constexpr int ACH = BM / 64;   // A staging chunks/thread: 2 or 4
    __shared__ unsigned short lA[2][BM * 64];
    __shared__ unsigned short lB[2][256 * 64];
    const int tid = threadIdx.x, lane = tid & 63, wid = tid >> 6;
    const int wr = wid >> 2, wc = wid & 3;
    const int g = lane >> 4, lr = lane & 15;
    const int nwg = gridDim.x;
    const int q = nwg >> 3; // bijective XCD swizzle, nwg % 8 == 0
    const int wg = (blockIdx.x & 7) * q + (blockIdx.x >> 3);
    const int bm = (wg % mtiles) * BM, bn = (wg / mtiles) * 256;

    f32x4 acc[MREP][4];
#pragma unroll
    for (int m = 0; m < MREP; ++m)
#pragma unroll
        for (int n = 0; n < 4; ++n) acc[m][n] = f32x4{0.f, 0.f, 0.f, 0.f};

    auto stage = [&](int buf, int k0) {
#pragma unroll
        for (int c = 0; c < ACH; ++c) { // A: BM rows x 128B
            const int soff = (c * 512 + tid) * 16;
            const int row = soff >> 7;
            const int chunk = ((soff >> 4) & 7) ^ (row & 7);
            __builtin_amdgcn_global_load_lds(
                (const __attribute__((address_space(1))) unsigned int*)
                    (A + (size_t)(bm + row) * K + k0 + chunk * 8),
                (__attribute__((address_space(3))) unsigned int*)
                    ((char*)lA[buf] + (unsigned)(c * 512 + wid * 64) * 16),
                16, 0, 0);
        }
#pragma unroll
        for (int c = 0; c < 4; ++c) { // B: 256 rows x 128B
            const int soff = (c * 512 + tid) * 16;
            const int row = soff >> 7;
            const int chunk = ((soff >> 4) & 7) ^ (row & 7);
            __builtin_amdgcn_global_load_lds(
                (const __attribute__((address_space(1))) unsigned int*)
                    (Bt + (size_t)(bn + row) * K + k0 + chunk * 8),
                (__attribute__((address_space(3))) unsigned int*)
                    ((char*)lB[buf] + (unsigned)(c * 512 + wid * 64) * 16),
                16, 0, 0);
        }
    };

    stage(0, 0); // prologue: tile 0's (ACH+4) loads per thread
    const int NT = K >> 6;
    for (int t = 0; t < NT; ++t) {
        const int buf = t & 1;
        // issue t+1's loads BEFORE waiting for t's -> counted retire
        if (t + 1 < NT) stage(buf ^ 1, (t + 1) << 6);
        __builtin_amdgcn_sched_barrier(0);
        if (t + 1 < NT) {
            if constexpr (BM == 128)
                asm volatile("s_waitcnt vmcnt(6)" ::: "memory"); // t's 6 landed
            else
                asm volatile("s_waitcnt vmcnt(8)" ::: "memory"); // t's 8 landed
        } else {
            asm volatile("s_waitcnt vmcnt(0)" ::: "memory");
        }
        __builtin_amdgcn_s_barrier(); // barrier#1: buf[t] visible to all waves
        __builtin_amdgcn_sched_barrier(0);
        const char* pa = (const char*)lA[buf];
        const char* pb = (const char*)lB[buf];
#pragma unroll
        for (int kk = 0; kk < 2; ++kk) {
            bf16x8 bfr[4];
#pragma unroll
            for (int n = 0; n < 4; ++n) {
                const int row = wc * 64 + n * 16 + lr;
                bfr[n] = *(const bf16x8*)(pb + row * 128 + ((((kk << 2) + g) ^ (row & 7)) << 4));
            }
#pragma unroll
            for (int mh = 0; mh < MREP / 4; ++mh) {
                bf16x8 af[4];
#pragma unroll
                for (int m = 0; m < 4; ++m) {
                    const int row = wr * (BM / 2) + (mh * 4 + m) * 16 + lr;
                    af[m] = *(const bf16x8*)(pa + row * 128 + ((((kk << 2) + g) ^ (row & 7)) << 4));
                }
                __builtin_amdgcn_s_setprio(1);
#pragma unroll
                for (int m = 0; m < 4; ++m)
#pragma unroll
                    for (int n = 0; n < 4; ++n)
                        acc[mh * 4 + m][n] = __builtin_amdgcn_mfma_f32_16x16x32_bf16(
                            af[m], bfr[n], acc[mh * 4 + m][n], 0, 0, 0);
                __builtin_amdgcn_s_setprio(0);
            }
        }
        __builtin_amdgcn_sched_barrier(0);
        __builtin_amdgcn_s_barrier(); // barrier#2: all waves done reading buf[t]
    }
#pragma unroll
    for (int m = 0; m < MREP; ++m)
#pragma unroll
        for (int n = 0; n < 4; ++n) {
            const int col = bn + wc * 64 + n * 16 + lr;
            const float bv = BIAS ? bias[col] : 0.f;
#pragma unroll
            for (int ii = 0; ii < 4; ++ii) {
                const int r = bm + wr * (BM / 2) + m * 16 + g * 4 + ii;
                const float v = acc[m][n][ii] + bv;
                if (OUTBF16)
                    ((unsigned short*)Cout)[(size_t)r * N + col] = f2bf(v);
                else
                    ((float*)Cout)[(size_t)r * N + col] = v;
            }
        }
}

// ---------------- RoPE in-place on Q and K of QKV buffer ----------------
// Q heads pre-scaled by SCALE_*log2(e): softmax runs in exp2 domain.
__global__ __launch_bounds__(256) void rope_kernel(unsigned short* __restrict__ QKV,
                                                   const int* __restrict__ positions) {
    const int tid = threadIdx.x;
    const int i = tid & 63;
    const int bt = blockIdx.x * 4 + (tid >> 6);
    const int head = blockIdx.y;
    unsigned short* base =
        QKV + (size_t)bt * NQKV + (head < NH ? head * HD : 2048 + (head - NH) * HD);
    const float pos = (float)positions[bt];
    const float invf = __expf(-(float)i * (9.21034037198e0f / 64.0f));
    const float f = pos * invf;
    const float sc = (head < NH) ? SCALE_ * LOG2E_ : 1.0f;
    const float c = cosf(f) * sc, s = sinf(f) * sc;
    const float x1 = bf2f(base[i]);
    const float x2 = bf2f(base[i + 64]);
    base[i] = f2bf(x1 * c - x2 * s);
    base[i + 64] = f2bf(x2 * c + x1 * s);
}

// ---------------- V transpose ----------------
__global__ __launch_bounds__(256) void vtrans_kernel(const unsigned short* __restrict__ QKV,
                                                     unsigned short* __restrict__ Vt) {
    __shared__ unsigned short l[16][128];
    const int tid = threadIdx.x;
    const int t0 = blockIdx.x * 16, kvh = blockIdx.y, b = blockIdx.z;
#pragma unroll
    for (int i = 0; i < 8; ++i) {
        const int t = (tid >> 7) + i * 2, d = tid & 127;
        l[t][d] = QKV[(size_t)(b * TSEQ + t0 + t) * NQKV + 2560 + kvh * HD + d];
    }
    __syncthreads();
    const int d = tid >> 1, th = (tid & 1) * 8;
    unsigned short tmp[8];
#pragma unroll
    for (int i = 0; i < 8; ++i) tmp[i] = l[th + i][d];
    *(int4*)&Vt[((size_t)(b * NKV + kvh) * HD + d) * TSEQ + t0 + th] = *(int4*)tmp;
}

// ---------------- causal GQA flash attention ----------------
// grid (8 pairs, NH, B), block 512 (8 waves x 16 q-rows = QBLK 128).
// r9 loop structure (stage(t+1) at top, compute, single __syncthreads drain).
// Swapped QK^T, scalar m/l, cvt_pk P-pack, exp2 via v_exp_f32.
__global__ __launch_bounds__(512) void attn_kernel(const unsigned short* __restrict__ QKV,
                                                   const unsigned short* __restrict__ Vt,
                                                   unsigned short* __restrict__ O) {
    __shared__ unsigned short lK[2][64 * HD]; // 2 x 16KB
    __shared__ unsigned short lV[2][HD * 64]; // 2 x 16KB
    __shared__ unsigned short lP[128 * 64];   // 16KB
    const int tid = threadIdx.x, lane = tid & 63, w = tid >> 6;
    const int g = lane >> 4, lr = lane & 15;
    const int pair = blockIdx.x;
    const int h = blockIdx.y, b = blockIdx.z;
    const int kvh = h >> 2;

    const unsigned short* kgbase = QKV + (size_t)(b * TSEQ) * NQKV + 2048 + kvh * HD;
    const unsigned short* vgbase = Vt + (size_t)(b * NKV + kvh) * HD * TSEQ;

    auto stage = [&](int buf, int k0) {
#pragma unroll
        for (int c = 0; c < 2; ++c) {
            const int soff = (c * 512 + tid) * 16;
            {
                const int row = soff >> 8;
                const int off = soff ^ ((row & 7) << 4);
                __builtin_amdgcn_global_load_lds(
                    (const __attribute__((address_space(1))) unsigned int*)
                        ((const char*)(kgbase + (size_t)(k0 + row) * NQKV) + (off & 255)),
                    (__attribute__((address_space(3))) unsigned int*)
                        ((char*)lK[buf] + (c * 512 + w * 64) * 16),
                    16, 0, 0);
            }
            {
                const int row = soff >> 7;
                const int off = soff ^ ((row & 7) << 4);
                __builtin_amdgcn_global_load_lds(
                    (const __attribute__((address_space(1))) unsigned int*)
                        ((const char*)(vgbase + (size_t)row * TSEQ + (size_t)k0) + (off & 127)),
                    (__attribute__((address_space(3))) unsigned int*)
                        ((char*)lV[buf] + (c * 512 + w * 64) * 16),
                    16, 0, 0);
            }
        }
    };

    int cur = 0;
#pragma unroll 1
    for (int ph = 0; ph < 2; ++ph) {
        const int q0 = (ph == 0 ? (15 - pair) : pair) * 128;
        const int qglob = q0 + 16 * w + lr; // this thread's q-row (softmax side)

        bf16x8 qf[4];
        {
            const unsigned short* qp =
                QKV + (size_t)(b * TSEQ + q0 + 16 * w + lr) * NQKV + h * HD;
#pragma unroll
            for (int kk = 0; kk < 4; ++kk) qf[kk] = *(const bf16x8*)(qp + kk * 32 + g * 8);
        }
        f32x4 oacc[8];
#pragma unroll
        for (int i = 0; i < 8; ++i) oacc[i] = f32x4{0.f, 0.f, 0.f, 0.f};
        float mrow = -1e30f, lrow = 0.f;

        stage(cur, 0);
        __syncthreads();

        const int klast = q0 + 64;
        for (int k0 = 0; k0 <= klast; k0 += 64) {
            const bool more = (k0 < klast);
            if (more) stage(cur ^ 1, k0 + 64); // async loads fly during compute

            const char* kb = (const char*)lK[cur];
            const char* vb = (const char*)lV[cur];

            // S^T = mfma(K, Q): s[j][ii] = S[key=k0+j*16+4g+ii][q=qglob]
            f32x4 s[4];
#pragma unroll
            for (int j = 0; j < 4; ++j) s[j] = f32x4{0.f, 0.f, 0.f, 0.f};
#pragma unroll
            for (int kk = 0; kk < 4; ++kk) {
#pragma unroll
                for (int j = 0; j < 4; ++j) {
                    const int row = j * 16 + lr;
                    const int boff = (row * 256 + kk * 64 + g * 16) ^ ((row & 7) << 4);
                    bf16x8 kf = *(const bf16x8*)(kb + boff);
                    s[j] = __builtin_amdgcn_mfma_f32_16x16x32_bf16(kf, qf[kk], s[j], 0, 0, 0);
                }
            }
            // causal mask: key > q
            if (k0 + 63 > q0 + 16 * w) {
#pragma unroll
                for (int j = 0; j < 4; ++j)
#pragma unroll
                    for (int ii = 0; ii < 4; ++ii)
                        if (k0 + j * 16 + 4 * g + ii > qglob) s[j][ii] = -1e30f;
            }
            // row max: 15 fmax + 2 shfl
            float mnew = s[0][0];
#pragma unroll
            for (int j = 0; j < 4; ++j)
#pragma unroll
                for (int ii = 0; ii < 4; ++ii) mnew = fmaxf(mnew, s[j][ii]);
            mnew = fmaxf(mnew, __shfl_xor(mnew, 16, 64));
            mnew = fmaxf(mnew, __shfl_xor(mnew, 32, 64));
            // defer-max rescale (exp2 domain; 11.5417 = 8*log2e)
            if (__any(mnew > mrow + 11.5417f)) {
                const float mN = fmaxf(mrow, mnew);
                const float resc = EXP2(mrow - mN);
                mrow = mN;
                lrow *= resc;
                float rsc[4];
#pragma unroll
                for (int ii = 0; ii < 4; ++ii) rsc[ii] = __shfl(resc, 4 * g + ii, 64);
#pragma unroll
                for (int nf = 0; nf < 8; ++nf)
#pragma unroll
                    for (int ii = 0; ii < 4; ++ii) oacc[nf][ii] *= rsc[ii];
            }
            // P = exp2(S - m); pack key-adjacent pairs; 8 b32 writes
            {
                const int pbase = (16 * w + lr) * 128;
                const int psw = (lr & 7) << 4;
#pragma unroll
                for (int j = 0; j < 4; ++j)
#pragma unroll
                    for (int pp = 0; pp < 2; ++pp) {
                        const float p0 = EXP2(s[j][2 * pp] - mrow);
                        const float p1 = EXP2(s[j][2 * pp + 1] - mrow);
                        lrow += p0 + p1;
                        unsigned pk;
                        asm("v_cvt_pk_bf16_f32 %0, %1, %2" : "=v"(pk) : "v"(p0), "v"(p1));
                        const int boff = (pbase + j * 32 + 8 * g + 4 * pp) ^ psw;
                        *(unsigned*)((char*)lP + boff) = pk;
                    }
            }
            // O += P @ V
#pragma unroll
            for (int kk = 0; kk < 2; ++kk) {
                const int arow = 16 * w + lr;
                const int aoff = (arow * 128 + kk * 64 + g * 16) ^ ((arow & 7) << 4);
                bf16x8 pf = *(const bf16x8*)((const char*)lP + aoff);
#pragma unroll
                for (int nf = 0; nf < 8; ++nf) {
                    const int vrow = nf * 16 + lr;
                    const int voff = (vrow * 128 + kk * 64 + g * 16) ^ ((vrow & 7) << 4);
                    bf16x8 vf = *(const bf16x8*)(vb + voff);
                    oacc[nf] = __builtin_amdgcn_mfma_f32_16x16x32_bf16(pf, vf, oacc[nf], 0, 0, 0);
                }
            }
            __syncthreads(); // drains staging vmcnt; buf^1 ready, buf reusable
            cur ^= 1;
        }
        // finalize: sum l across g-groups; fetch per-output-row inverses
        lrow += __shfl_xor(lrow, 16, 64);
        lrow += __shfl_xor(lrow, 32, 64);
        float linv[4];
#pragma unroll
        for (int ii = 0; ii < 4; ++ii) linv[ii] = 1.0f / __shfl(lrow, 4 * g + ii, 64);
#pragma unroll
        for (int nf = 0; nf < 8; ++nf)
#pragma unroll
            for (int ii = 0; ii < 4; ++ii) {
                const int qrow = q0 + 16 * w + 4 * g + ii;
                const int col = h * HD + nf * 16 + lr;
                O[(size_t)(b * TSEQ + qrow) * (NH * HD) + col] = f2bf(oacc[nf][ii] * linv[ii]);
            }
    }
}

extern "C" void kernel_launch(void* const* d_in, const int* in_sizes, int n_in,
                              void* d_out, int out_size, void* d_ws, size_t ws_size,
                              hipStream_t stream) {
    const float* hs = (const float*)d_in[0];
    const int* positions = (const int*)d_in[1];
    const float* wq = (const float*)d_in[2];
    const float* bq = (const float*)d_in[3];
    const float* wk = (const float*)d_in[4];
    const float* bk = (const float*)d_in[5];
    const float* wv = (const float*)d_in[6];
    const float* bv = (const float*)d_in[7];
    const float* wo = (const float*)d_in[8];
    float* out = (float*)d_out;

    const size_t SZ_XB = (size_t)8192 * 2048 * 2;
    const size_t SZ_WQKV = (size_t)3072 * 2048 * 2;
    const size_t SZ_WOT = (size_t)2048 * 2048 * 2;
    const size_t SZ_BIAS = 3072 * 4;
    const size_t SZ_QKV = (size_t)8192 * 3072 * 2;
    const size_t SZ_VT = (size_t)BATCH * NKV * HD * TSEQ * 2;
    const size_t SZ_OB = (size_t)8192 * 2048 * 2;

    char* ws = (char*)d_ws;
    unsigned short *Xb, *WqkvT, *WoT, *QKVb, *Vtb, *Ob;
    float* bqkv;
    const size_t need = SZ_XB + SZ_WQKV + SZ_WOT + SZ_BIAS + SZ_QKV + SZ_VT + SZ_OB + 2048;
    size_t off = 0;
    auto take = [&](size_t n) { char* p = ws + off; off += (n + 255) & ~(size_t)255; return p; };
    if (ws_size >= need) {
        Xb = (unsigned short*)take(SZ_XB);
        WqkvT = (unsigned short*)take(SZ_WQKV);
        Vtb = (unsigned short*)take(SZ_VT);
        WoT = (unsigned short*)take(SZ_WOT);
        bqkv = (float*)take(SZ_BIAS);
        QKVb = (unsigned short*)take(SZ_QKV);
        Ob = (unsigned short*)take(SZ_OB);
    } else {
        char* od = (char*)d_out;
        Xb = (unsigned short*)od;
        WqkvT = (unsigned short*)(od + SZ_XB);
        Vtb = (unsigned short*)(od + SZ_XB + SZ_WQKV);
        WoT = (unsigned short*)take(SZ_WOT);
        bqkv = (float*)take(SZ_BIAS);
        QKVb = (unsigned short*)take(SZ_QKV);
        Ob = (unsigned short*)take(SZ_OB);
    }

    xconv<<<16384, 256, 0, stream>>>(hs, Xb);
    wtrans_kernel<<<dim3(32, 32), 256, 0, stream>>>(wq, WqkvT, 2048, 2048);
    wtrans_kernel<<<dim3(8, 32), 256, 0, stream>>>(wk, WqkvT + (size_t)2048 * 2048, 512, 2048);
    wtrans_kernel<<<dim3(8, 32), 256, 0, stream>>>(wv, WqkvT + (size_t)2560 * 2048, 512, 2048);
    wtrans_kernel<<<dim3(32, 32), 256, 0, stream>>>(wo, WoT, 2048, 2048);
    bias_concat<<<12, 256, 0, stream>>>(bq, bk, bv, bqkv);
    gemm256<128, true, true><<<768, 512, 0, stream>>>(Xb, WqkvT, bqkv, QKVb, 8192, 3072, 2048, 64);
    rope_kernel<<<dim3(2048, 20), 256, 0, stream>>>(QKVb, positions);
    vtrans_kernel<<<dim3(128, 4, 4), 256, 0, stream>>>(QKVb, Vtb);
    attn_kernel<<<dim3(8, 16, 4), 512, 0, stream>>>(QKVb, Vtb, Ob);
    gemm256<256, false, false><<<256, 512, 0, stream>>>(Ob, WoT, nullptr, out, 8192, 2048, 2048, 32);
}

// Round 17
// 400.387 us; speedup vs baseline: 1.0814x; 1.0814x over previous
//
#include <hip/hip_runtime.h>
#include <hip/hip_bf16.h>

#define TSEQ 2048
#define BATCH 4
#define NH 16
#define NKV 4
#define HD 128
#define NQKV 3072
#define SCALE_ 0.08838834764831845f
#define LOG2E_ 1.44269504088896f

#if __has_builtin(__builtin_amdgcn_exp2f)
#define EXP2(x) __builtin_amdgcn_exp2f(x)
#else
#define EXP2(x) __expf((x) * 0.6931471805599453f)
#endif

typedef __bf16 bf16x8 __attribute__((ext_vector_type(8)));
typedef float f32x4 __attribute__((ext_vector_type(4)));

__device__ __forceinline__ unsigned short f2bf(float f) {
    union { float f; unsigned u; } v; v.f = f;
    unsigned r = v.u + 0x7fffu + ((v.u >> 16) & 1u);
    return (unsigned short)(r >> 16);
}
__device__ __forceinline__ float bf2f(unsigned short b) {
    union { unsigned u; float f; } v; v.u = ((unsigned)b) << 16; return v.f;
}

// ---------------- X fp32 -> bf16 (vectorized) ----------------
__global__ __launch_bounds__(256) void xconv(const float* __restrict__ in,
                                             unsigned short* __restrict__ out) {
    const size_t i = (size_t)blockIdx.x * 256 + threadIdx.x; // 4 floats per thread
    const float4 v = ((const float4*)in)[i];
    union { unsigned short u[4]; int2 p; } o;
    o.u[0] = f2bf(v.x); o.u[1] = f2bf(v.y); o.u[2] = f2bf(v.z); o.u[3] = f2bf(v.w);
    ((int2*)out)[i] = o.p;
}

// ------------- weight transpose f32 [K][inN] -> bf16 [inN-rows][K] -------------
// grid (inN/64, K/64), block 256
__global__ __launch_bounds__(256) void wtrans_kernel(const float* __restrict__ in,
                                                     unsigned short* __restrict__ out,
                                                     int inN, int K) {
    __shared__ unsigned short l[64][65];
    const int n0 = blockIdx.x * 64, k0 = blockIdx.y * 64;
    const int tid = threadIdx.x;
    const int r = tid >> 2, c0 = (tid & 3) * 16;
#pragma unroll
    for (int i = 0; i < 16; i += 4) {
        float4 v = *(const float4*)&in[(size_t)(k0 + r) * inN + n0 + c0 + i];
        l[c0 + i + 0][r] = f2bf(v.x);
        l[c0 + i + 1][r] = f2bf(v.y);
        l[c0 + i + 2][r] = f2bf(v.z);
        l[c0 + i + 3][r] = f2bf(v.w);
    }
    __syncthreads();
    unsigned short tmp[16];
#pragma unroll
    for (int i = 0; i < 16; ++i) tmp[i] = l[r][c0 + i];
    *(int4*)&out[(size_t)(n0 + r) * K + k0 + c0] = *(int4*)&tmp[0];
    *(int4*)&out[(size_t)(n0 + r) * K + k0 + c0 + 8] = *(int4*)&tmp[8];
}

// ---------------- bias concat ----------------
__global__ __launch_bounds__(256) void bias_concat(const float* __restrict__ bq,
                                                   const float* __restrict__ bk,
                                                   const float* __restrict__ bv,
                                                   float* __restrict__ out) {
    int i = blockIdx.x * 256 + threadIdx.x; // 3072
    out[i] = (i < 2048) ? bq[i] : ((i < 2560) ? bk[i - 2048] : bv[i - 2560]);
}

// ---------------- 256x256 counted-vmcnt GEMM (r7/r15 version, best measured) ----
// BK=64, 8 waves (2M x 4N), wave tile 128x64, acc 8x4 f32x4.
template <bool BIAS, bool OUTBF16>
__global__ __launch_bounds__(512) void gemm256(const unsigned short* __restrict__ A,
                                               const unsigned short* __restrict__ Bt,
                                               const float* __restrict__ bias,
                                               void* __restrict__ Cout,
                                               int M, int N, int K, int mtiles) {
    __shared__ unsigned short lA[2][256 * 64];
    __shared__ unsigned short lB[2][256 * 64];
    const int tid = threadIdx.x, lane = tid & 63, wid = tid >> 6;
    const int wr = wid >> 2, wc = wid & 3;
    const int g = lane >> 4, lr = lane & 15;
    const int nwg = gridDim.x;
    const int q = nwg >> 3; // bijective XCD swizzle, nwg % 8 == 0
    const int wg = (blockIdx.x & 7) * q + (blockIdx.x >> 3);
    const int bm = (wg % mtiles) * 256, bn = (wg / mtiles) * 256;

    f32x4 acc[8][4];
#pragma unroll
    for (int m = 0; m < 8; ++m)
#pragma unroll
        for (int n = 0; n < 4; ++n) acc[m][n] = f32x4{0.f, 0.f, 0.f, 0.f};

    auto stage = [&](int buf, int k0) {
#pragma unroll
        for (int c = 0; c < 4; ++c) {
            const int soff = (c * 512 + tid) * 16; // linear LDS byte this lane fills
            const int row = soff >> 7;             // 0..255 (128B rows)
            const int chunk = ((soff >> 4) & 7) ^ (row & 7); // source pre-swizzle
            const unsigned lbase = (unsigned)(c * 512 + wid * 64) * 16;
            __builtin_amdgcn_global_load_lds(
                (const __attribute__((address_space(1))) unsigned int*)
                    (A + (size_t)(bm + row) * K + k0 + chunk * 8),
                (__attribute__((address_space(3))) unsigned int*)((char*)lA[buf] + lbase),
                16, 0, 0);
            __builtin_amdgcn_global_load_lds(
                (const __attribute__((address_space(1))) unsigned int*)
                    (Bt + (size_t)(bn + row) * K + k0 + chunk * 8),
                (__attribute__((address_space(3))) unsigned int*)((char*)lB[buf] + lbase),
                16, 0, 0);
        }
    };

    stage(0, 0); // prologue: tile 0's 8 loads per wave
    const int NT = K >> 6;
    for (int t = 0; t < NT; ++t) {
        const int buf = t & 1;
        // issue t+1's 8 loads BEFORE waiting for t's -> counted retire
        if (t + 1 < NT) stage(buf ^ 1, (t + 1) << 6);
        __builtin_amdgcn_sched_barrier(0);
        if (t + 1 < NT) {
            asm volatile("s_waitcnt vmcnt(8)" ::: "memory"); // t's 8 landed; t+1's fly
        } else {
            asm volatile("s_waitcnt vmcnt(0)" ::: "memory");
        }
        __builtin_amdgcn_s_barrier(); // barrier#1: buf[t] visible to all waves
        __builtin_amdgcn_sched_barrier(0);
        const char* pa = (const char*)lA[buf];
        const char* pb = (const char*)lB[buf];
#pragma unroll
        for (int kk = 0; kk < 2; ++kk) {
            bf16x8 bfr[4];
#pragma unroll
            for (int n = 0; n < 4; ++n) {
                const int row = wc * 64 + n * 16 + lr;
                bfr[n] = *(const bf16x8*)(pb + row * 128 + ((((kk << 2) + g) ^ (row & 7)) << 4));
            }
#pragma unroll
            for (int mh = 0; mh < 2; ++mh) {
                bf16x8 af[4];
#pragma unroll
                for (int m = 0; m < 4; ++m) {
                    const int row = wr * 128 + (mh * 4 + m) * 16 + lr;
                    af[m] = *(const bf16x8*)(pa + row * 128 + ((((kk << 2) + g) ^ (row & 7)) << 4));
                }
                __builtin_amdgcn_s_setprio(1);
#pragma unroll
                for (int m = 0; m < 4; ++m)
#pragma unroll
                    for (int n = 0; n < 4; ++n)
                        acc[mh * 4 + m][n] = __builtin_amdgcn_mfma_f32_16x16x32_bf16(
                            af[m], bfr[n], acc[mh * 4 + m][n], 0, 0, 0);
                __builtin_amdgcn_s_setprio(0);
            }
        }
        __builtin_amdgcn_sched_barrier(0);
        __builtin_amdgcn_s_barrier(); // barrier#2: all waves done reading buf[t]
    }
#pragma unroll
    for (int m = 0; m < 8; ++m)
#pragma unroll
        for (int n = 0; n < 4; ++n) {
            const int col = bn + wc * 64 + n * 16 + lr;
            const float bv = BIAS ? bias[col] : 0.f;
#pragma unroll
            for (int ii = 0; ii < 4; ++ii) {
                const int r = bm + wr * 128 + m * 16 + g * 4 + ii;
                const float v = acc[m][n][ii] + bv;
                if (OUTBF16)
                    ((unsigned short*)Cout)[(size_t)r * N + col] = f2bf(v);
                else
                    ((float*)Cout)[(size_t)r * N + col] = v;
            }
        }
}

// ---------------- RoPE in-place on Q and K of QKV buffer ----------------
// Q heads pre-scaled by SCALE_*log2(e): softmax runs in exp2 domain.
__global__ __launch_bounds__(256) void rope_kernel(unsigned short* __restrict__ QKV,
                                                   const int* __restrict__ positions) {
    const int tid = threadIdx.x;
    const int i = tid & 63;
    const int bt = blockIdx.x * 4 + (tid >> 6);
    const int head = blockIdx.y;
    unsigned short* base =
        QKV + (size_t)bt * NQKV + (head < NH ? head * HD : 2048 + (head - NH) * HD);
    const float pos = (float)positions[bt];
    const float invf = __expf(-(float)i * (9.21034037198e0f / 64.0f));
    const float f = pos * invf;
    const float sc = (head < NH) ? SCALE_ * LOG2E_ : 1.0f;
    const float c = cosf(f) * sc, s = sinf(f) * sc;
    const float x1 = bf2f(base[i]);
    const float x2 = bf2f(base[i + 64]);
    base[i] = f2bf(x1 * c - x2 * s);
    base[i + 64] = f2bf(x2 * c + x1 * s);
}

// ---------------- V transpose ----------------
__global__ __launch_bounds__(256) void vtrans_kernel(const unsigned short* __restrict__ QKV,
                                                     unsigned short* __restrict__ Vt) {
    __shared__ unsigned short l[16][128];
    const int tid = threadIdx.x;
    const int t0 = blockIdx.x * 16, kvh = blockIdx.y, b = blockIdx.z;
#pragma unroll
    for (int i = 0; i < 8; ++i) {
        const int t = (tid >> 7) + i * 2, d = tid & 127;
        l[t][d] = QKV[(size_t)(b * TSEQ + t0 + t) * NQKV + 2560 + kvh * HD + d];
    }
    __syncthreads();
    const int d = tid >> 1, th = (tid & 1) * 8;
    unsigned short tmp[8];
#pragma unroll
    for (int i = 0; i < 8; ++i) tmp[i] = l[th + i][d];
    *(int4*)&Vt[((size_t)(b * NKV + kvh) * HD + d) * TSEQ + t0 + th] = *(int4*)tmp;
}

// ---------------- causal GQA flash attention ----------------
// 1-D grid 512 blocks, block 512 (8 waves x 16 q-rows = QBLK 128).
// XCD-locality swizzle: all 32 blocks sharing one (kvh,b) K/V set carry the
// same id%8 (XCD residue) -> each XCD reads 2 of 16 combos (8MB vs 32MB).
// r9/r15 loop (stage at top, compute, single __syncthreads drain); swapped
// QK^T, scalar m/l, cvt_pk P-pack, exp2 via v_exp_f32.
__global__ __launch_bounds__(512) void attn_kernel(const unsigned short* __restrict__ QKV,
                                                   const unsigned short* __restrict__ Vt,
                                                   unsigned short* __restrict__ O) {
    __shared__ unsigned short lK[2][64 * HD]; // 2 x 16KB
    __shared__ unsigned short lV[2][HD * 64]; // 2 x 16KB
    __shared__ unsigned short lP[128 * 64];   // 16KB
    const int tid = threadIdx.x, lane = tid & 63, w = tid >> 6;
    const int g = lane >> 4, lr = lane & 15;
    // bijective id -> (pair, h, b) with combo pinned to id%8
    const int id = blockIdx.x;                          // 0..511
    const int combo = (id & 7) | (((id >> 3) & 1) << 3); // 0..15
    const int kvh = combo & 3, b = combo >> 2;
    const int widx = id >> 4;                            // 0..31
    const int h = kvh * 4 + (widx & 3);
    const int pair = widx >> 2;                          // 0..7

    const unsigned short* kgbase = QKV + (size_t)(b * TSEQ) * NQKV + 2048 + kvh * HD;
    const unsigned short* vgbase = Vt + (size_t)(b * NKV + kvh) * HD * TSEQ;

    auto stage = [&](int buf, int k0) {
#pragma unroll
        for (int c = 0; c < 2; ++c) {
            const int soff = (c * 512 + tid) * 16;
            {
                const int row = soff >> 8;
                const int off = soff ^ ((row & 7) << 4);
                __builtin_amdgcn_global_load_lds(
                    (const __attribute__((address_space(1))) unsigned int*)
                        ((const char*)(kgbase + (size_t)(k0 + row) * NQKV) + (off & 255)),
                    (__attribute__((address_space(3))) unsigned int*)
                        ((char*)lK[buf] + (c * 512 + w * 64) * 16),
                    16, 0, 0);
            }
            {
                const int row = soff >> 7;
                const int off = soff ^ ((row & 7) << 4);
                __builtin_amdgcn_global_load_lds(
                    (const __attribute__((address_space(1))) unsigned int*)
                        ((const char*)(vgbase + (size_t)row * TSEQ + (size_t)k0) + (off & 127)),
                    (__attribute__((address_space(3))) unsigned int*)
                        ((char*)lV[buf] + (c * 512 + w * 64) * 16),
                    16, 0, 0);
            }
        }
    };

    int cur = 0;
#pragma unroll 1
    for (int ph = 0; ph < 2; ++ph) {
        const int q0 = (ph == 0 ? (15 - pair) : pair) * 128;
        const int qglob = q0 + 16 * w + lr; // this thread's q-row (softmax side)

        bf16x8 qf[4];
        {
            const unsigned short* qp =
                QKV + (size_t)(b * TSEQ + q0 + 16 * w + lr) * NQKV + h * HD;
#pragma unroll
            for (int kk = 0; kk < 4; ++kk) qf[kk] = *(const bf16x8*)(qp + kk * 32 + g * 8);
        }
        f32x4 oacc[8];
#pragma unroll
        for (int i = 0; i < 8; ++i) oacc[i] = f32x4{0.f, 0.f, 0.f, 0.f};
        float mrow = -1e30f, lrow = 0.f;

        stage(cur, 0);
        __syncthreads();

        const int klast = q0 + 64;
        for (int k0 = 0; k0 <= klast; k0 += 64) {
            const bool more = (k0 < klast);
            if (more) stage(cur ^ 1, k0 + 64); // async loads fly during compute

            const char* kb = (const char*)lK[cur];
            const char* vb = (const char*)lV[cur];

            // S^T = mfma(K, Q): s[j][ii] = S[key=k0+j*16+4g+ii][q=qglob]
            f32x4 s[4];
#pragma unroll
            for (int j = 0; j < 4; ++j) s[j] = f32x4{0.f, 0.f, 0.f, 0.f};
#pragma unroll
            for (int kk = 0; kk < 4; ++kk) {
#pragma unroll
                for (int j = 0; j < 4; ++j) {
                    const int row = j * 16 + lr;
                    const int boff = (row * 256 + kk * 64 + g * 16) ^ ((row & 7) << 4);
                    bf16x8 kf = *(const bf16x8*)(kb + boff);
                    s[j] = __builtin_amdgcn_mfma_f32_16x16x32_bf16(kf, qf[kk], s[j], 0, 0, 0);
                }
            }
            // causal mask: key > q
            if (k0 + 63 > q0 + 16 * w) {
#pragma unroll
                for (int j = 0; j < 4; ++j)
#pragma unroll
                    for (int ii = 0; ii < 4; ++ii)
                        if (k0 + j * 16 + 4 * g + ii > qglob) s[j][ii] = -1e30f;
            }
            // row max: 15 fmax + 2 shfl
            float mnew = s[0][0];
#pragma unroll
            for (int j = 0; j < 4; ++j)
#pragma unroll
                for (int ii = 0; ii < 4; ++ii) mnew = fmaxf(mnew, s[j][ii]);
            mnew = fmaxf(mnew, __shfl_xor(mnew, 16, 64));
            mnew = fmaxf(mnew, __shfl_xor(mnew, 32, 64));
            // defer-max rescale (exp2 domain; 11.5417 = 8*log2e)
            if (__any(mnew > mrow + 11.5417f)) {
                const float mN = fmaxf(mrow, mnew);
                const float resc = EXP2(mrow - mN);
                mrow = mN;
                lrow *= resc;
                float rsc[4];
#pragma unroll
                for (int ii = 0; ii < 4; ++ii) rsc[ii] = __shfl(resc, 4 * g + ii, 64);
#pragma unroll
                for (int nf = 0; nf < 8; ++nf)
#pragma unroll
                    for (int ii = 0; ii < 4; ++ii) oacc[nf][ii] *= rsc[ii];
            }
            // P = exp2(S - m); pack key-adjacent pairs; 8 b32 writes
            {
                const int pbase = (16 * w + lr) * 128;
                const int psw = (lr & 7) << 4;
#pragma unroll
                for (int j = 0; j < 4; ++j)
#pragma unroll
                    for (int pp = 0; pp < 2; ++pp) {
                        const float p0 = EXP2(s[j][2 * pp] - mrow);
                        const float p1 = EXP2(s[j][2 * pp + 1] - mrow);
                        lrow += p0 + p1;
                        unsigned pk;
                        asm("v_cvt_pk_bf16_f32 %0, %1, %2" : "=v"(pk) : "v"(p0), "v"(p1));
                        const int boff = (pbase + j * 32 + 8 * g + 4 * pp) ^ psw;
                        *(unsigned*)((char*)lP + boff) = pk;
                    }
            }
            // O += P @ V
#pragma unroll
            for (int kk = 0; kk < 2; ++kk) {
                const int arow = 16 * w + lr;
                const int aoff = (arow * 128 + kk * 64 + g * 16) ^ ((arow & 7) << 4);
                bf16x8 pf = *(const bf16x8*)((const char*)lP + aoff);
#pragma unroll
                for (int nf = 0; nf < 8; ++nf) {
                    const int vrow = nf * 16 + lr;
                    const int voff = (vrow * 128 + kk * 64 + g * 16) ^ ((vrow & 7) << 4);
                    bf16x8 vf = *(const bf16x8*)(vb + voff);
                    oacc[nf] = __builtin_amdgcn_mfma_f32_16x16x32_bf16(pf, vf, oacc[nf], 0, 0, 0);
                }
            }
            __syncthreads(); // drains staging vmcnt; buf^1 ready, buf reusable
            cur ^= 1;
        }
        // finalize: sum l across g-groups; fetch per-output-row inverses
        lrow += __shfl_xor(lrow, 16, 64);
        lrow += __shfl_xor(lrow, 32, 64);
        float linv[4];
#pragma unroll
        for (int ii = 0; ii < 4; ++ii) linv[ii] = 1.0f / __shfl(lrow, 4 * g + ii, 64);
#pragma unroll
        for (int nf = 0; nf < 8; ++nf)
#pragma unroll
            for (int ii = 0; ii < 4; ++ii) {
                const int qrow = q0 + 16 * w + 4 * g + ii;
                const int col = h * HD + nf * 16 + lr;
                O[(size_t)(b * TSEQ + qrow) * (NH * HD) + col] = f2bf(oacc[nf][ii] * linv[ii]);
            }
    }
}

extern "C" void kernel_launch(void* const* d_in, const int* in_sizes, int n_in,
                              void* d_out, int out_size, void* d_ws, size_t ws_size,
                              hipStream_t stream) {
    const float* hs = (const float*)d_in[0];
    const int* positions = (const int*)d_in[1];
    const float* wq = (const float*)d_in[2];
    const float* bq = (const float*)d_in[3];
    const float* wk = (const float*)d_in[4];
    const float* bk = (const float*)d_in[5];
    const float* wv = (const float*)d_in[6];
    const float* bv = (const float*)d_in[7];
    const float* wo = (const float*)d_in[8];
    float* out = (float*)d_out;

    const size_t SZ_XB = (size_t)8192 * 2048 * 2;
    const size_t SZ_WQKV = (size_t)3072 * 2048 * 2;
    const size_t SZ_WOT = (size_t)2048 * 2048 * 2;
    const size_t SZ_BIAS = 3072 * 4;
    const size_t SZ_QKV = (size_t)8192 * 3072 * 2;
    const size_t SZ_VT = (size_t)BATCH * NKV * HD * TSEQ * 2;
    const size_t SZ_OB = (size_t)8192 * 2048 * 2;

    char* ws = (char*)d_ws;
    unsigned short *Xb, *WqkvT, *WoT, *QKVb, *Vtb, *Ob;
    float* bqkv;
    const size_t need = SZ_XB + SZ_WQKV + SZ_WOT + SZ_BIAS + SZ_QKV + SZ_VT + SZ_OB + 2048;
    size_t off = 0;
    auto take = [&](size_t n) { char* p = ws + off; off += (n + 255) & ~(size_t)255; return p; };
    if (ws_size >= need) {
        Xb = (unsigned short*)take(SZ_XB);
        WqkvT = (unsigned short*)take(SZ_WQKV);
        Vtb = (unsigned short*)take(SZ_VT);
        WoT = (unsigned short*)take(SZ_WOT);
        bqkv = (float*)take(SZ_BIAS);
        QKVb = (unsigned short*)take(SZ_QKV);
        Ob = (unsigned short*)take(SZ_OB);
    } else {
        char* od = (char*)d_out;
        Xb = (unsigned short*)od;
        WqkvT = (unsigned short*)(od + SZ_XB);
        Vtb = (unsigned short*)(od + SZ_XB + SZ_WQKV);
        WoT = (unsigned short*)take(SZ_WOT);
        bqkv = (float*)take(SZ_BIAS);
        QKVb = (unsigned short*)take(SZ_QKV);
        Ob = (unsigned short*)take(SZ_OB);
    }

    xconv<<<16384, 256, 0, stream>>>(hs, Xb);
    wtrans_kernel<<<dim3(32, 32), 256, 0, stream>>>(wq, WqkvT, 2048, 2048);
    wtrans_kernel<<<dim3(8, 32), 256, 0, stream>>>(wk, WqkvT + (size_t)2048 * 2048, 512, 2048);
    wtrans_kernel<<<dim3(8, 32), 256, 0, stream>>>(wv, WqkvT + (size_t)2560 * 2048, 512, 2048);
    wtrans_kernel<<<dim3(32, 32), 256, 0, stream>>>(wo, WoT, 2048, 2048);
    bias_concat<<<12, 256, 0, stream>>>(bq, bk, bv, bqkv);
    gemm256<true, true><<<384, 512, 0, stream>>>(Xb, WqkvT, bqkv, QKVb, 8192, 3072, 2048, 32);
    rope_kernel<<<dim3(2048, 20), 256, 0, stream>>>(QKVb, positions);
    vtrans_kernel<<<dim3(128, 4, 4), 256, 0, stream>>>(QKVb, Vtb);
    attn_kernel<<<512, 512, 0, stream>>>(QKVb, Vtb, Ob);
    gemm256<false, false><<<256, 512, 0, stream>>>(Ob, WoT, nullptr, out, 8192, 2048, 2048, 32);
}

// Round 18
// 397.925 us; speedup vs baseline: 1.0881x; 1.0062x over previous
//
#include <hip/hip_runtime.h>
#include <hip/hip_bf16.h>

#define TSEQ 2048
#define BATCH 4
#define NH 16
#define NKV 4
#define HD 128
#define NQKV 3072
#define SCALE_ 0.08838834764831845f
#define LOG2E_ 1.44269504088896f

#if __has_builtin(__builtin_amdgcn_exp2f)
#define EXP2(x) __builtin_amdgcn_exp2f(x)
#else
#define EXP2(x) __expf((x) * 0.6931471805599453f)
#endif

typedef __bf16 bf16x8 __attribute__((ext_vector_type(8)));
typedef float f32x4 __attribute__((ext_vector_type(4)));

__device__ __forceinline__ unsigned short f2bf(float f) {
    union { float f; unsigned u; } v; v.f = f;
    unsigned r = v.u + 0x7fffu + ((v.u >> 16) & 1u);
    return (unsigned short)(r >> 16);
}
__device__ __forceinline__ float bf2f(unsigned short b) {
    union { unsigned u; float f; } v; v.u = ((unsigned)b) << 16; return v.f;
}

// ---------------- X fp32 -> bf16 (vectorized) ----------------
__global__ __launch_bounds__(256) void xconv(const float* __restrict__ in,
                                             unsigned short* __restrict__ out) {
    const size_t i = (size_t)blockIdx.x * 256 + threadIdx.x; // 4 floats per thread
    const float4 v = ((const float4*)in)[i];
    union { unsigned short u[4]; int2 p; } o;
    o.u[0] = f2bf(v.x); o.u[1] = f2bf(v.y); o.u[2] = f2bf(v.z); o.u[3] = f2bf(v.w);
    ((int2*)out)[i] = o.p;
}

// ------------- weight transpose f32 [K][inN] -> bf16 [inN-rows][K] -------------
// grid (inN/64, K/64), block 256
__global__ __launch_bounds__(256) void wtrans_kernel(const float* __restrict__ in,
                                                     unsigned short* __restrict__ out,
                                                     int inN, int K) {
    __shared__ unsigned short l[64][65];
    const int n0 = blockIdx.x * 64, k0 = blockIdx.y * 64;
    const int tid = threadIdx.x;
    const int r = tid >> 2, c0 = (tid & 3) * 16;
#pragma unroll
    for (int i = 0; i < 16; i += 4) {
        float4 v = *(const float4*)&in[(size_t)(k0 + r) * inN + n0 + c0 + i];
        l[c0 + i + 0][r] = f2bf(v.x);
        l[c0 + i + 1][r] = f2bf(v.y);
        l[c0 + i + 2][r] = f2bf(v.z);
        l[c0 + i + 3][r] = f2bf(v.w);
    }
    __syncthreads();
    unsigned short tmp[16];
#pragma unroll
    for (int i = 0; i < 16; ++i) tmp[i] = l[r][c0 + i];
    *(int4*)&out[(size_t)(n0 + r) * K + k0 + c0] = *(int4*)&tmp[0];
    *(int4*)&out[(size_t)(n0 + r) * K + k0 + c0 + 8] = *(int4*)&tmp[8];
}

// ---------------- bias concat ----------------
__global__ __launch_bounds__(256) void bias_concat(const float* __restrict__ bq,
                                                   const float* __restrict__ bk,
                                                   const float* __restrict__ bv,
                                                   float* __restrict__ out) {
    int i = blockIdx.x * 256 + threadIdx.x; // 3072
    out[i] = (i < 2048) ? bq[i] : ((i < 2560) ? bk[i - 2048] : bv[i - 2560]);
}

// ---------------- 256x256 counted-vmcnt GEMM (r7/r15 core, N-first mapping) -----
// BK=64, 8 waves (2M x 4N), wave tile 128x64, acc 8x4 f32x4.
// N-first block mapping: each XCD's contiguous chunk covers few M-rows x all
// N-panels -> per-XCD L2 footprint 16MB (QKV) / 12MB (O) vs 34MB M-first.
template <bool BIAS, bool OUTBF16>
__global__ __launch_bounds__(512) void gemm256(const unsigned short* __restrict__ A,
                                               const unsigned short* __restrict__ Bt,
                                               const float* __restrict__ bias,
                                               void* __restrict__ Cout,
                                               int M, int N, int K, int ntiles) {
    __shared__ unsigned short lA[2][256 * 64];
    __shared__ unsigned short lB[2][256 * 64];
    const int tid = threadIdx.x, lane = tid & 63, wid = tid >> 6;
    const int wr = wid >> 2, wc = wid & 3;
    const int g = lane >> 4, lr = lane & 15;
    const int nwg = gridDim.x;
    const int q = nwg >> 3; // bijective XCD swizzle, nwg % 8 == 0
    const int wg = (blockIdx.x & 7) * q + (blockIdx.x >> 3);
    const int bn = (wg % ntiles) * 256, bm = (wg / ntiles) * 256;

    f32x4 acc[8][4];
#pragma unroll
    for (int m = 0; m < 8; ++m)
#pragma unroll
        for (int n = 0; n < 4; ++n) acc[m][n] = f32x4{0.f, 0.f, 0.f, 0.f};

    auto stage = [&](int buf, int k0) {
#pragma unroll
        for (int c = 0; c < 4; ++c) {
            const int soff = (c * 512 + tid) * 16; // linear LDS byte this lane fills
            const int row = soff >> 7;             // 0..255 (128B rows)
            const int chunk = ((soff >> 4) & 7) ^ (row & 7); // source pre-swizzle
            const unsigned lbase = (unsigned)(c * 512 + wid * 64) * 16;
            __builtin_amdgcn_global_load_lds(
                (const __attribute__((address_space(1))) unsigned int*)
                    (A + (size_t)(bm + row) * K + k0 + chunk * 8),
                (__attribute__((address_space(3))) unsigned int*)((char*)lA[buf] + lbase),
                16, 0, 0);
            __builtin_amdgcn_global_load_lds(
                (const __attribute__((address_space(1))) unsigned int*)
                    (Bt + (size_t)(bn + row) * K + k0 + chunk * 8),
                (__attribute__((address_space(3))) unsigned int*)((char*)lB[buf] + lbase),
                16, 0, 0);
        }
    };

    stage(0, 0); // prologue: tile 0's 8 loads per wave
    const int NT = K >> 6;
    for (int t = 0; t < NT; ++t) {
        const int buf = t & 1;
        // issue t+1's 8 loads BEFORE waiting for t's -> counted retire
        if (t + 1 < NT) stage(buf ^ 1, (t + 1) << 6);
        __builtin_amdgcn_sched_barrier(0);
        if (t + 1 < NT) {
            asm volatile("s_waitcnt vmcnt(8)" ::: "memory"); // t's 8 landed; t+1's fly
        } else {
            asm volatile("s_waitcnt vmcnt(0)" ::: "memory");
        }
        __builtin_amdgcn_s_barrier(); // barrier#1: buf[t] visible to all waves
        __builtin_amdgcn_sched_barrier(0);
        const char* pa = (const char*)lA[buf];
        const char* pb = (const char*)lB[buf];
#pragma unroll
        for (int kk = 0; kk < 2; ++kk) {
            bf16x8 bfr[4];
#pragma unroll
            for (int n = 0; n < 4; ++n) {
                const int row = wc * 64 + n * 16 + lr;
                bfr[n] = *(const bf16x8*)(pb + row * 128 + ((((kk << 2) + g) ^ (row & 7)) << 4));
            }
#pragma unroll
            for (int mh = 0; mh < 2; ++mh) {
                bf16x8 af[4];
#pragma unroll
                for (int m = 0; m < 4; ++m) {
                    const int row = wr * 128 + (mh * 4 + m) * 16 + lr;
                    af[m] = *(const bf16x8*)(pa + row * 128 + ((((kk << 2) + g) ^ (row & 7)) << 4));
                }
                __builtin_amdgcn_s_setprio(1);
#pragma unroll
                for (int m = 0; m < 4; ++m)
#pragma unroll
                    for (int n = 0; n < 4; ++n)
                        acc[mh * 4 + m][n] = __builtin_amdgcn_mfma_f32_16x16x32_bf16(
                            af[m], bfr[n], acc[mh * 4 + m][n], 0, 0, 0);
                __builtin_amdgcn_s_setprio(0);
            }
        }
        __builtin_amdgcn_sched_barrier(0);
        __builtin_amdgcn_s_barrier(); // barrier#2: all waves done reading buf[t]
    }
#pragma unroll
    for (int m = 0; m < 8; ++m)
#pragma unroll
        for (int n = 0; n < 4; ++n) {
            const int col = bn + wc * 64 + n * 16 + lr;
            const float bv = BIAS ? bias[col] : 0.f;
#pragma unroll
            for (int ii = 0; ii < 4; ++ii) {
                const int r = bm + wr * 128 + m * 16 + g * 4 + ii;
                const float v = acc[m][n][ii] + bv;
                if (OUTBF16)
                    ((unsigned short*)Cout)[(size_t)r * N + col] = f2bf(v);
                else
                    ((float*)Cout)[(size_t)r * N + col] = v;
            }
        }
}

// ---------------- RoPE in-place on Q and K of QKV buffer ----------------
// Q heads pre-scaled by SCALE_*log2(e): softmax runs in exp2 domain.
__global__ __launch_bounds__(256) void rope_kernel(unsigned short* __restrict__ QKV,
                                                   const int* __restrict__ positions) {
    const int tid = threadIdx.x;
    const int i = tid & 63;
    const int bt = blockIdx.x * 4 + (tid >> 6);
    const int head = blockIdx.y;
    unsigned short* base =
        QKV + (size_t)bt * NQKV + (head < NH ? head * HD : 2048 + (head - NH) * HD);
    const float pos = (float)positions[bt];
    const float invf = __expf(-(float)i * (9.21034037198e0f / 64.0f));
    const float f = pos * invf;
    const float sc = (head < NH) ? SCALE_ * LOG2E_ : 1.0f;
    const float c = cosf(f) * sc, s = sinf(f) * sc;
    const float x1 = bf2f(base[i]);
    const float x2 = bf2f(base[i + 64]);
    base[i] = f2bf(x1 * c - x2 * s);
    base[i + 64] = f2bf(x2 * c + x1 * s);
}

// ---------------- V transpose ----------------
__global__ __launch_bounds__(256) void vtrans_kernel(const unsigned short* __restrict__ QKV,
                                                     unsigned short* __restrict__ Vt) {
    __shared__ unsigned short l[16][128];
    const int tid = threadIdx.x;
    const int t0 = blockIdx.x * 16, kvh = blockIdx.y, b = blockIdx.z;
#pragma unroll
    for (int i = 0; i < 8; ++i) {
        const int t = (tid >> 7) + i * 2, d = tid & 127;
        l[t][d] = QKV[(size_t)(b * TSEQ + t0 + t) * NQKV + 2560 + kvh * HD + d];
    }
    __syncthreads();
    const int d = tid >> 1, th = (tid & 1) * 8;
    unsigned short tmp[8];
#pragma unroll
    for (int i = 0; i < 8; ++i) tmp[i] = l[th + i][d];
    *(int4*)&Vt[((size_t)(b * NKV + kvh) * HD + d) * TSEQ + t0 + th] = *(int4*)tmp;
}

// ---------------- causal GQA flash attention ----------------
// 1-D grid 512 blocks, block 512 (8 waves x 16 q-rows = QBLK 128).
// XCD-locality swizzle: all 32 blocks sharing one (kvh,b) K/V set carry the
// same id%8 (XCD residue). r9/r15 loop; swapped QK^T; scalar m/l; cvt_pk;
// exp2 via v_exp_f32.
__global__ __launch_bounds__(512) void attn_kernel(const unsigned short* __restrict__ QKV,
                                                   const unsigned short* __restrict__ Vt,
                                                   unsigned short* __restrict__ O) {
    __shared__ unsigned short lK[2][64 * HD]; // 2 x 16KB
    __shared__ unsigned short lV[2][HD * 64]; // 2 x 16KB
    __shared__ unsigned short lP[128 * 64];   // 16KB
    const int tid = threadIdx.x, lane = tid & 63, w = tid >> 6;
    const int g = lane >> 4, lr = lane & 15;
    // bijective id -> (pair, h, b) with combo pinned to id%8
    const int id = blockIdx.x;                          // 0..511
    const int combo = (id & 7) | (((id >> 3) & 1) << 3); // 0..15
    const int kvh = combo & 3, b = combo >> 2;
    const int widx = id >> 4;                            // 0..31
    const int h = kvh * 4 + (widx & 3);
    const int pair = widx >> 2;                          // 0..7

    const unsigned short* kgbase = QKV + (size_t)(b * TSEQ) * NQKV + 2048 + kvh * HD;
    const unsigned short* vgbase = Vt + (size_t)(b * NKV + kvh) * HD * TSEQ;

    auto stage = [&](int buf, int k0) {
#pragma unroll
        for (int c = 0; c < 2; ++c) {
            const int soff = (c * 512 + tid) * 16;
            {
                const int row = soff >> 8;
                const int off = soff ^ ((row & 7) << 4);
                __builtin_amdgcn_global_load_lds(
                    (const __attribute__((address_space(1))) unsigned int*)
                        ((const char*)(kgbase + (size_t)(k0 + row) * NQKV) + (off & 255)),
                    (__attribute__((address_space(3))) unsigned int*)
                        ((char*)lK[buf] + (c * 512 + w * 64) * 16),
                    16, 0, 0);
            }
            {
                const int row = soff >> 7;
                const int off = soff ^ ((row & 7) << 4);
                __builtin_amdgcn_global_load_lds(
                    (const __attribute__((address_space(1))) unsigned int*)
                        ((const char*)(vgbase + (size_t)row * TSEQ + (size_t)k0) + (off & 127)),
                    (__attribute__((address_space(3))) unsigned int*)
                        ((char*)lV[buf] + (c * 512 + w * 64) * 16),
                    16, 0, 0);
            }
        }
    };

    int cur = 0;
#pragma unroll 1
    for (int ph = 0; ph < 2; ++ph) {
        const int q0 = (ph == 0 ? (15 - pair) : pair) * 128;
        const int qglob = q0 + 16 * w + lr; // this thread's q-row (softmax side)

        bf16x8 qf[4];
        {
            const unsigned short* qp =
                QKV + (size_t)(b * TSEQ + q0 + 16 * w + lr) * NQKV + h * HD;
#pragma unroll
            for (int kk = 0; kk < 4; ++kk) qf[kk] = *(const bf16x8*)(qp + kk * 32 + g * 8);
        }
        f32x4 oacc[8];
#pragma unroll
        for (int i = 0; i < 8; ++i) oacc[i] = f32x4{0.f, 0.f, 0.f, 0.f};
        float mrow = -1e30f, lrow = 0.f;

        stage(cur, 0);
        __syncthreads();

        const int klast = q0 + 64;
        for (int k0 = 0; k0 <= klast; k0 += 64) {
            const bool more = (k0 < klast);
            if (more) stage(cur ^ 1, k0 + 64); // async loads fly during compute

            const char* kb = (const char*)lK[cur];
            const char* vb = (const char*)lV[cur];

            // S^T = mfma(K, Q): s[j][ii] = S[key=k0+j*16+4g+ii][q=qglob]
            f32x4 s[4];
#pragma unroll
            for (int j = 0; j < 4; ++j) s[j] = f32x4{0.f, 0.f, 0.f, 0.f};
#pragma unroll
            for (int kk = 0; kk < 4; ++kk) {
#pragma unroll
                for (int j = 0; j < 4; ++j) {
                    const int row = j * 16 + lr;
                    const int boff = (row * 256 + kk * 64 + g * 16) ^ ((row & 7) << 4);
                    bf16x8 kf = *(const bf16x8*)(kb + boff);
                    s[j] = __builtin_amdgcn_mfma_f32_16x16x32_bf16(kf, qf[kk], s[j], 0, 0, 0);
                }
            }
            // causal mask: key > q
            if (k0 + 63 > q0 + 16 * w) {
#pragma unroll
                for (int j = 0; j < 4; ++j)
#pragma unroll
                    for (int ii = 0; ii < 4; ++ii)
                        if (k0 + j * 16 + 4 * g + ii > qglob) s[j][ii] = -1e30f;
            }
            // row max: 15 fmax + 2 shfl
            float mnew = s[0][0];
#pragma unroll
            for (int j = 0; j < 4; ++j)
#pragma unroll
                for (int ii = 0; ii < 4; ++ii) mnew = fmaxf(mnew, s[j][ii]);
            mnew = fmaxf(mnew, __shfl_xor(mnew, 16, 64));
            mnew = fmaxf(mnew, __shfl_xor(mnew, 32, 64));
            // defer-max rescale (exp2 domain; 11.5417 = 8*log2e)
            if (__any(mnew > mrow + 11.5417f)) {
                const float mN = fmaxf(mrow, mnew);
                const float resc = EXP2(mrow - mN);
                mrow = mN;
                lrow *= resc;
                float rsc[4];
#pragma unroll
                for (int ii = 0; ii < 4; ++ii) rsc[ii] = __shfl(resc, 4 * g + ii, 64);
#pragma unroll
                for (int nf = 0; nf < 8; ++nf)
#pragma unroll
                    for (int ii = 0; ii < 4; ++ii) oacc[nf][ii] *= rsc[ii];
            }
            // P = exp2(S - m); pack key-adjacent pairs; 8 b32 writes
            {
                const int pbase = (16 * w + lr) * 128;
                const int psw = (lr & 7) << 4;
#pragma unroll
                for (int j = 0; j < 4; ++j)
#pragma unroll
                    for (int pp = 0; pp < 2; ++pp) {
                        const float p0 = EXP2(s[j][2 * pp] - mrow);
                        const float p1 = EXP2(s[j][2 * pp + 1] - mrow);
                        lrow += p0 + p1;
                        unsigned pk;
                        asm("v_cvt_pk_bf16_f32 %0, %1, %2" : "=v"(pk) : "v"(p0), "v"(p1));
                        const int boff = (pbase + j * 32 + 8 * g + 4 * pp) ^ psw;
                        *(unsigned*)((char*)lP + boff) = pk;
                    }
            }
            // O += P @ V
#pragma unroll
            for (int kk = 0; kk < 2; ++kk) {
                const int arow = 16 * w + lr;
                const int aoff = (arow * 128 + kk * 64 + g * 16) ^ ((arow & 7) << 4);
                bf16x8 pf = *(const bf16x8*)((const char*)lP + aoff);
#pragma unroll
                for (int nf = 0; nf < 8; ++nf) {
                    const int vrow = nf * 16 + lr;
                    const int voff = (vrow * 128 + kk * 64 + g * 16) ^ ((vrow & 7) << 4);
                    bf16x8 vf = *(const bf16x8*)(vb + voff);
                    oacc[nf] = __builtin_amdgcn_mfma_f32_16x16x32_bf16(pf, vf, oacc[nf], 0, 0, 0);
                }
            }
            __syncthreads(); // drains staging vmcnt; buf^1 ready, buf reusable
            cur ^= 1;
        }
        // finalize: sum l across g-groups; fetch per-output-row inverses
        lrow += __shfl_xor(lrow, 16, 64);
        lrow += __shfl_xor(lrow, 32, 64);
        float linv[4];
#pragma unroll
        for (int ii = 0; ii < 4; ++ii) linv[ii] = 1.0f / __shfl(lrow, 4 * g + ii, 64);
#pragma unroll
        for (int nf = 0; nf < 8; ++nf)
#pragma unroll
            for (int ii = 0; ii < 4; ++ii) {
                const int qrow = q0 + 16 * w + 4 * g + ii;
                const int col = h * HD + nf * 16 + lr;
                O[(size_t)(b * TSEQ + qrow) * (NH * HD) + col] = f2bf(oacc[nf][ii] * linv[ii]);
            }
    }
}

extern "C" void kernel_launch(void* const* d_in, const int* in_sizes, int n_in,
                              void* d_out, int out_size, void* d_ws, size_t ws_size,
                              hipStream_t stream) {
    const float* hs = (const float*)d_in[0];
    const int* positions = (const int*)d_in[1];
    const float* wq = (const float*)d_in[2];
    const float* bq = (const float*)d_in[3];
    const float* wk = (const float*)d_in[4];
    const float* bk = (const float*)d_in[5];
    const float* wv = (const float*)d_in[6];
    const float* bv = (const float*)d_in[7];
    const float* wo = (const float*)d_in[8];
    float* out = (float*)d_out;

    const size_t SZ_XB = (size_t)8192 * 2048 * 2;
    const size_t SZ_WQKV = (size_t)3072 * 2048 * 2;
    const size_t SZ_WOT = (size_t)2048 * 2048 * 2;
    const size_t SZ_BIAS = 3072 * 4;
    const size_t SZ_QKV = (size_t)8192 * 3072 * 2;
    const size_t SZ_VT = (size_t)BATCH * NKV * HD * TSEQ * 2;
    const size_t SZ_OB = (size_t)8192 * 2048 * 2;

    char* ws = (char*)d_ws;
    unsigned short *Xb, *WqkvT, *WoT, *QKVb, *Vtb, *Ob;
    float* bqkv;
    const size_t need = SZ_XB + SZ_WQKV + SZ_WOT + SZ_BIAS + SZ_QKV + SZ_VT + SZ_OB + 2048;
    size_t off = 0;
    auto take = [&](size_t n) { char* p = ws + off; off += (n + 255) & ~(size_t)255; return p; };
    if (ws_size >= need) {
        Xb = (unsigned short*)take(SZ_XB);
        WqkvT = (unsigned short*)take(SZ_WQKV);
        Vtb = (unsigned short*)take(SZ_VT);
        WoT = (unsigned short*)take(SZ_WOT);
        bqkv = (float*)take(SZ_BIAS);
        QKVb = (unsigned short*)take(SZ_QKV);
        Ob = (unsigned short*)take(SZ_OB);
    } else {
        char* od = (char*)d_out;
        Xb = (unsigned short*)od;
        WqkvT = (unsigned short*)(od + SZ_XB);
        Vtb = (unsigned short*)(od + SZ_XB + SZ_WQKV);
        WoT = (unsigned short*)take(SZ_WOT);
        bqkv = (float*)take(SZ_BIAS);
        QKVb = (unsigned short*)take(SZ_QKV);
        Ob = (unsigned short*)take(SZ_OB);
    }

    xconv<<<16384, 256, 0, stream>>>(hs, Xb);
    wtrans_kernel<<<dim3(32, 32), 256, 0, stream>>>(wq, WqkvT, 2048, 2048);
    wtrans_kernel<<<dim3(8, 32), 256, 0, stream>>>(wk, WqkvT + (size_t)2048 * 2048, 512, 2048);
    wtrans_kernel<<<dim3(8, 32), 256, 0, stream>>>(wv, WqkvT + (size_t)2560 * 2048, 512, 2048);
    wtrans_kernel<<<dim3(32, 32), 256, 0, stream>>>(wo, WoT, 2048, 2048);
    bias_concat<<<12, 256, 0, stream>>>(bq, bk, bv, bqkv);
    gemm256<true, true><<<384, 512, 0, stream>>>(Xb, WqkvT, bqkv, QKVb, 8192, 3072, 2048, 12);
    rope_kernel<<<dim3(2048, 20), 256, 0, stream>>>(QKVb, positions);
    vtrans_kernel<<<dim3(128, 4, 4), 256, 0, stream>>>(QKVb, Vtb);
    attn_kernel<<<512, 512, 0, stream>>>(QKVb, Vtb, Ob);
    gemm256<false, false><<<256, 512, 0, stream>>>(Ob, WoT, nullptr, out, 8192, 2048, 2048, 8);
}